// Round 4
// baseline (218.477 us; speedup 1.0000x reference)
//
#include <hip/hip_runtime.h>
#include <stdint.h>

// EventAwareAttention: B=8, S=2048, H=DK=512
// d_out = [context fp32 (8*2048*512)] ++ [attn fp32 (8*2048*2048)]
// Pipeline: k0 cvt fp32->fp16; k1 QKV proj (fp16 MFMA); k2e QK^T + exp +
// per-row partial sums (exp-scores fp16 stashed in the SECOND half of each
// attn row's 8KB slot); k4_fused: normalize+attn-write+PV in one pass.
// ws (h16 units, A=8388608): Xf[0,A) | Wf[A,A+W3) | Qf | Kf | Par(2MB f32) | Vt[4A,5A)

#define Bn 8
#define Sn 2048
#define Hn 512
#define BM 128
#define BN 128
#define BKk 64
#define QT 64
#define HT 512
#define KT 64

typedef unsigned short u16;
typedef _Float16 h16;
typedef __attribute__((ext_vector_type(8))) _Float16 f16x8;
typedef __attribute__((ext_vector_type(4))) _Float16 f16x4;
typedef __attribute__((ext_vector_type(4))) float f32x4;

__device__ __forceinline__ f32x4 mfma16h(f16x8 a, f16x8 b, f32x4 c) {
  return __builtin_amdgcn_mfma_f32_16x16x32_f16(a, b, c, 0, 0, 0);
}
__device__ __forceinline__ void g2l16(const void* g, void* l) {
  __builtin_amdgcn_global_load_lds(
      (const __attribute__((address_space(1))) void*)g,
      (__attribute__((address_space(3))) void*)l,
      16, 0, 0);
}

// ---------------------------------------------------------------------------
// K0: fp32 -> fp16 for X and Wq/Wk/Wv.
// ---------------------------------------------------------------------------
__global__ __launch_bounds__(256) void k0_cvt(
    const float* __restrict__ X,
    const float* __restrict__ Wq, const float* __restrict__ Wk,
    const float* __restrict__ Wv,
    h16* __restrict__ Xf, h16* __restrict__ Wf) {
  const int y = blockIdx.y;
  const float* src;
  h16* dst;
  int n;
  if (y == 0) {
    src = X; dst = Xf; n = 16384 * 512;
  } else {
    src = (y == 1) ? Wq : ((y == 2) ? Wk : Wv);
    dst = Wf + (size_t)(y - 1) * 512 * 512;
    n = 512 * 512;
  }
  const int i = (blockIdx.x * 256 + threadIdx.x) * 8;
  if (i >= n) return;
  float4 v0 = *(const float4*)(src + i);
  float4 v1 = *(const float4*)(src + i + 4);
  f16x8 h;
  h[0] = (h16)v0.x; h[1] = (h16)v0.y; h[2] = (h16)v0.z; h[3] = (h16)v0.w;
  h[4] = (h16)v1.x; h[5] = (h16)v1.y; h[6] = (h16)v1.z; h[7] = (h16)v1.w;
  *(f16x8*)(dst + i) = h;
}

// ---------------------------------------------------------------------------
// K1: QKV projection fp16 GEMM. Q,K row-major; V transposed Vt[b][o][s].
// ---------------------------------------------------------------------------
__global__ __launch_bounds__(256) void k1_proj(
    const h16* __restrict__ Xf, const h16* __restrict__ Wf,
    const float* __restrict__ bq, const float* __restrict__ bk,
    const float* __restrict__ bv,
    h16* __restrict__ Qf, h16* __restrict__ Kf, h16* __restrict__ Vt) {
  __shared__ h16 lA[BM * BKk], lB[BM * BKk];
  const int t = threadIdx.x;
  const int lane = t & 63;
  const int wid = t >> 6;
  const int wr = wid >> 1, wc = wid & 1;
  const int tn = blockIdx.x;
  const int m0 = blockIdx.y * BM;
  const int mat = tn >> 2;
  const int o0 = (tn & 3) * BN;
  const float* bsel = (mat == 0) ? bq : ((mat == 1) ? bk : bv);
  const size_t arow0 = (size_t)m0;
  const size_t brow0 = (size_t)mat * 512 + o0;

  f32x4 acc[4][4];
  const f32x4 fz = {0.f, 0.f, 0.f, 0.f};
#pragma unroll
  for (int m = 0; m < 4; ++m)
#pragma unroll
    for (int n = 0; n < 4; ++n) acc[m][n] = fz;

  const int srow = lane >> 3;
  const int scol = ((lane & 7) ^ srow) << 3;

  for (int k0 = 0; k0 < Hn; k0 += BKk) {
    __syncthreads();
#pragma unroll
    for (int j = 0; j < 4; ++j) {
      const int ci = wid * 4 + j;
      const int row = ci * 8 + srow;
      g2l16(Xf + (arow0 + row) * Hn + k0 + scol, &lA[ci * 512]);
      g2l16(Wf + (brow0 + row) * Hn + k0 + scol, &lB[ci * 512]);
    }
    __syncthreads();
#pragma unroll
    for (int ks = 0; ks < 2; ++ks) {
      f16x8 af[4], bf[4];
#pragma unroll
      for (int m = 0; m < 4; ++m) {
        const int row = wr * 64 + m * 16 + (lane & 15);
        const int col8 = ks * 4 + (lane >> 4);
        af[m] = *(const f16x8*)&lA[row * BKk + ((col8 ^ (row & 7)) << 3)];
      }
#pragma unroll
      for (int n = 0; n < 4; ++n) {
        const int row = wc * 64 + n * 16 + (lane & 15);
        const int col8 = ks * 4 + (lane >> 4);
        bf[n] = *(const f16x8*)&lB[row * BKk + ((col8 ^ (row & 7)) << 3)];
      }
#pragma unroll
      for (int m = 0; m < 4; ++m)
#pragma unroll
        for (int n = 0; n < 4; ++n)
          acc[m][n] = mfma16h(af[m], bf[n], acc[m][n]);
    }
  }
#pragma unroll
  for (int n = 0; n < 4; ++n) {
    const int o = o0 + wc * 64 + n * 16 + (lane & 15);
    const float bias = bsel[o];
#pragma unroll
    for (int m = 0; m < 4; ++m) {
      const int ib = m0 + wr * 64 + m * 16 + ((lane >> 4) << 2);
      if (mat < 2) {
        h16* Dst = (mat == 0) ? Qf : Kf;
#pragma unroll
        for (int r = 0; r < 4; ++r)
          Dst[(size_t)(ib + r) * Hn + o] = (h16)(acc[m][n][r] + bias);
      } else {
        const int bb = ib >> 11, s = ib & 2047;
        f16x4 p;
#pragma unroll
        for (int r = 0; r < 4; ++r) p[r] = (h16)(acc[m][n][r] + bias);
        *(f16x4*)&Vt[((size_t)bb * Hn + o) * Sn + s] = p;
      }
    }
  }
}

// ---------------------------------------------------------------------------
// K2e: exp(QK^T * scale) fp16 -> second half of each attn-row slot (elem
// offset row*4096 + 2048 + k), plus deterministic per-row partial sums
// Par[b][q][32] (slot = blockIdx.x*2 + wc, sums 64 keys each).
// No max subtraction: |score| <~ 7 -> exp <~ 1100 << fp16 max.
// ---------------------------------------------------------------------------
__global__ __launch_bounds__(256) void k2_scores(
    const h16* __restrict__ Qf, const h16* __restrict__ Kf,
    const float* __restrict__ shape_ratio,
    h16* __restrict__ S16, float* __restrict__ Par) {
  __shared__ h16 lA[BM * BKk], lB[BM * BKk];
  const int t = threadIdx.x;
  const int lane = t & 63;
  const int wid = t >> 6;
  const int wr = wid >> 1, wc = wid & 1;
  const int b = blockIdx.z;
  const int n0 = blockIdx.x * BN;
  const int m0 = blockIdx.y * BM;
  const size_t qrow0 = (size_t)b * Sn + m0;
  const size_t krow0 = (size_t)b * Sn + n0;

  f32x4 acc[4][4];
  const f32x4 fz = {0.f, 0.f, 0.f, 0.f};
#pragma unroll
  for (int m = 0; m < 4; ++m)
#pragma unroll
    for (int n = 0; n < 4; ++n) acc[m][n] = fz;

  const int srow = lane >> 3;
  const int scol = ((lane & 7) ^ srow) << 3;

  for (int k0 = 0; k0 < Hn; k0 += BKk) {
    __syncthreads();
#pragma unroll
    for (int j = 0; j < 4; ++j) {
      const int ci = wid * 4 + j;
      const int row = ci * 8 + srow;
      g2l16(Qf + (qrow0 + row) * Hn + k0 + scol, &lA[ci * 512]);
      g2l16(Kf + (krow0 + row) * Hn + k0 + scol, &lB[ci * 512]);
    }
    __syncthreads();
#pragma unroll
    for (int ks = 0; ks < 2; ++ks) {
      f16x8 af[4], bf[4];
#pragma unroll
      for (int m = 0; m < 4; ++m) {
        const int row = wr * 64 + m * 16 + (lane & 15);
        const int col8 = ks * 4 + (lane >> 4);
        af[m] = *(const f16x8*)&lA[row * BKk + ((col8 ^ (row & 7)) << 3)];
      }
#pragma unroll
      for (int n = 0; n < 4; ++n) {
        const int row = wc * 64 + n * 16 + (lane & 15);
        const int col8 = ks * 4 + (lane >> 4);
        bf[n] = *(const f16x8*)&lB[row * BKk + ((col8 ^ (row & 7)) << 3)];
      }
#pragma unroll
      for (int m = 0; m < 4; ++m)
#pragma unroll
        for (int n = 0; n < 4; ++n)
          acc[m][n] = mfma16h(af[m], bf[n], acc[m][n]);
    }
  }
  const float scale = shape_ratio[0] * 0.044194173824159216f;  // 1/sqrt(512)
  float psum[4][4];
#pragma unroll
  for (int m = 0; m < 4; ++m)
#pragma unroll
    for (int r = 0; r < 4; ++r) psum[m][r] = 0.f;

#pragma unroll
  for (int n = 0; n < 4; ++n) {
    const int kk = n0 + wc * 64 + n * 16 + (lane & 15);
#pragma unroll
    for (int m = 0; m < 4; ++m) {
      const int q = m0 + wr * 64 + m * 16 + ((lane >> 4) << 2);
#pragma unroll
      for (int r = 0; r < 4; ++r) {
        const float e = __expf(acc[m][n][r] * scale);
        S16[((size_t)b * Sn + q + r) * 4096 + 2048 + kk] = (h16)e;
        psum[m][r] += e;
      }
    }
  }
  // reduce across the 16 lanes holding the same rows (lane bits 0..3)
#pragma unroll
  for (int m = 0; m < 4; ++m)
#pragma unroll
    for (int r = 0; r < 4; ++r) {
      float s = psum[m][r];
      s += __shfl_xor(s, 1);
      s += __shfl_xor(s, 2);
      s += __shfl_xor(s, 4);
      s += __shfl_xor(s, 8);
      psum[m][r] = s;
    }
  if ((lane & 15) == 0) {
    const int slot = (n0 >> 6) + wc;   // blockIdx.x*2 + wc
#pragma unroll
    for (int m = 0; m < 4; ++m) {
      const int q = m0 + wr * 64 + m * 16 + ((lane >> 4) << 2);
#pragma unroll
      for (int r = 0; r < 4; ++r)
        Par[((size_t)b * Sn + q + r) * 32 + slot] = psum[m][r];
    }
  }
}

// ---------------------------------------------------------------------------
// K4_fused: per block (batch b, 64 q-rows): reduce partials -> inv_sum;
// K-loop: stage exp-tile (64x64) + V-tile (512x64) double-buffered, PV MFMA
// on raw exp, write normalized fp32 attn tile in-loop; ctx = acc * inv_sum.
// blockIdx.x = batch -> XCD affinity (Vt slice L2-resident).
// ---------------------------------------------------------------------------
__global__ __launch_bounds__(256) void k4_fused(
    const h16* S16, const float* __restrict__ Par,
    const h16* __restrict__ Vt, float* attnF, float* __restrict__ Ctx) {
  __shared__ h16 lE[2][QT * KT];     // 2 x 8 KB
  __shared__ h16 lV[2][HT * KT];     // 2 x 64 KB
  __shared__ float inv[QT];
  const int t = threadIdx.x;
  const int lane = t & 63;
  const int wid = t >> 6;
  const int b = blockIdx.x;
  const int m0 = blockIdx.y * QT;

  if (t < QT) {
    const float* p = Par + ((size_t)b * Sn + m0 + t) * 32;
    float s = 0.f;
#pragma unroll
    for (int i = 0; i < 32; ++i) s += p[i];
    inv[t] = 1.0f / s;
  }

  f32x4 acc[4][8];
  const f32x4 fz = {0.f, 0.f, 0.f, 0.f};
#pragma unroll
  for (int mf = 0; mf < 4; ++mf)
#pragma unroll
    for (int nf = 0; nf < 8; ++nf) acc[mf][nf] = fz;

  const int srow = lane >> 3;
  const int sc8 = (lane & 7) ^ srow;       // pre-swizzled source col8

  auto stage = [&](int tk, int bufi) {
#pragma unroll
    for (int j = 0; j < 2; ++j) {
      const int ci = wid * 2 + j;          // 0..7, 8 rows each
      const int row = ci * 8 + srow;
      g2l16(S16 + ((size_t)(b * Sn + m0 + row)) * 4096 + 2048 + tk + sc8 * 8,
            &lE[bufi][ci * 512]);
    }
#pragma unroll
    for (int j = 0; j < 16; ++j) {
      const int ci = wid * 16 + j;         // 0..63, 8 h-rows each
      const int row = ci * 8 + srow;
      g2l16(Vt + ((size_t)b * Hn + row) * Sn + tk + sc8 * 8,
            &lV[bufi][ci * 512]);
    }
  };

  stage(0, 0);
  __syncthreads();
  int cur = 0;
  for (int tt = 0; tt < Sn / KT; ++tt) {
    if (tt + 1 < Sn / KT) stage((tt + 1) * KT, cur ^ 1);
#pragma unroll
    for (int ks = 0; ks < 2; ++ks) {
      const int col8 = ks * 4 + (lane >> 4);
      f16x8 av[4], bv[8];
#pragma unroll
      for (int mf = 0; mf < 4; ++mf) {
        const int row = mf * 16 + (lane & 15);
        av[mf] = *(const f16x8*)&lE[cur][row * KT + ((col8 ^ (row & 7)) << 3)];
      }
#pragma unroll
      for (int nf = 0; nf < 8; ++nf) {
        const int row = wid * 128 + nf * 16 + (lane & 15);
        bv[nf] = *(const f16x8*)&lV[cur][row * KT + ((col8 ^ (row & 7)) << 3)];
      }
#pragma unroll
      for (int mf = 0; mf < 4; ++mf)
#pragma unroll
        for (int nf = 0; nf < 8; ++nf)
          acc[mf][nf] = mfma16h(av[mf], bv[nf], acc[mf][nf]);
    }
    // normalized fp32 attn write for this key tile
    {
      const int row = t >> 2, cg = t & 3;
      const float iv = inv[row];
      const f16x8 e0 =
          *(const f16x8*)&lE[cur][row * KT + (((cg * 2) ^ (row & 7)) << 3)];
      const f16x8 e1 =
          *(const f16x8*)&lE[cur][row * KT + (((cg * 2 + 1) ^ (row & 7)) << 3)];
      float* dst = attnF + ((size_t)(b * Sn + m0 + row)) * Sn + tt * KT + cg * 16;
      float4 o0 = make_float4((float)e0[0] * iv, (float)e0[1] * iv,
                              (float)e0[2] * iv, (float)e0[3] * iv);
      float4 o1 = make_float4((float)e0[4] * iv, (float)e0[5] * iv,
                              (float)e0[6] * iv, (float)e0[7] * iv);
      float4 o2 = make_float4((float)e1[0] * iv, (float)e1[1] * iv,
                              (float)e1[2] * iv, (float)e1[3] * iv);
      float4 o3 = make_float4((float)e1[4] * iv, (float)e1[5] * iv,
                              (float)e1[6] * iv, (float)e1[7] * iv);
      *(float4*)dst = o0;
      *(float4*)(dst + 4) = o1;
      *(float4*)(dst + 8) = o2;
      *(float4*)(dst + 12) = o3;
    }
    __syncthreads();
    cur ^= 1;
  }
  // context epilogue (normalize by inv_sum here)
#pragma unroll
  for (int nf = 0; nf < 8; ++nf) {
    const int h = wid * 128 + nf * 16 + (lane & 15);
#pragma unroll
    for (int mf = 0; mf < 4; ++mf) {
      const int qb = mf * 16 + ((lane >> 4) << 2);
#pragma unroll
      for (int r = 0; r < 4; ++r)
        Ctx[((size_t)(b * Sn + m0 + qb + r)) * Hn + h] =
            acc[mf][nf][r] * inv[qb + r];
    }
  }
}

// ---------------------------------------------------------------------------
extern "C" void kernel_launch(void* const* d_in, const int* in_sizes, int n_in,
                              void* d_out, int out_size, void* d_ws, size_t ws_size,
                              hipStream_t stream) {
  const float* X  = (const float*)d_in[0];
  // d_in[1] = event_flag (cancels in softmax), d_in[2] = lengths (unused)
  const float* Wq = (const float*)d_in[3];
  const float* bq = (const float*)d_in[4];
  const float* Wk = (const float*)d_in[5];
  const float* bk = (const float*)d_in[6];
  const float* Wv = (const float*)d_in[7];
  const float* bv = (const float*)d_in[8];
  // d_in[9] = event_weight (cancels in softmax)
  const float* shape_ratio = (const float*)d_in[10];

  float* ctx  = (float*)d_out;
  float* attn = ctx + (size_t)Bn * Sn * Hn;

  h16* ws = (h16*)d_ws;
  const size_t A = (size_t)Bn * Sn * Hn;   // 8,388,608
  const size_t W3 = (size_t)3 * 512 * 512; // 786,432
  h16* Xf = ws;
  h16* Wf = ws + A;
  h16* Qf = ws + A + W3;
  h16* Kf = ws + 2 * A + W3;
  float* Par = (float*)(ws + 3 * A + W3);  // 8*2048*32 floats = 2 MB
  h16* Vt = ws + 4 * A;

  k0_cvt<<<dim3(4096, 4), 256, 0, stream>>>(X, Wq, Wk, Wv, Xf, Wf);
  k1_proj<<<dim3(12, 128), 256, 0, stream>>>(Xf, Wf, bq, bk, bv, Qf, Kf, Vt);
  k2_scores<<<dim3(16, 16, 8), 256, 0, stream>>>(Qf, Kf, shape_ratio,
                                                 (h16*)attn, Par);
  k4_fused<<<dim3(8, 32), 256, 0, stream>>>((const h16*)attn, Par, Vt,
                                            attn, ctx);
}

// Round 5
// 216.503 us; speedup vs baseline: 1.0091x; 1.0091x over previous
//
#include <hip/hip_runtime.h>
#include <stdint.h>

// EventAwareAttention: B=8, S=2048, H=DK=512
// d_out = [context fp32 (8*2048*512)] ++ [attn fp32 (8*2048*2048)]
// Pipeline:
//   k0  cvt fp32->fp16 (X, W)
//   k1  QKV proj fp16 GEMM (Q,K row-major; V transposed Vt[b][h][s])
//   k2e QK^T + exp + per-row partial sums; exp fp16 stashed in the SECOND
//       half of each attn row's 8KB fp32 slot (elem off row*4096+2048)
//   k4p PV GEMM on raw exp, ctx = acc * inv(rowsum)   [reads exp stash]
//   k3n normalize: attn fp32 rows = exp * inv         [clobbers exp stash]
// ws (h16 units, A=8388608): Xf[0,A) | Wf | Qf | Kf | Par(2MB f32) | Vt[4A,5A)

#define Bn 8
#define Sn 2048
#define Hn 512
#define BM 128
#define BN 128
#define BKk 64

typedef unsigned short u16;
typedef _Float16 h16;
typedef __attribute__((ext_vector_type(8))) _Float16 f16x8;
typedef __attribute__((ext_vector_type(4))) _Float16 f16x4;
typedef __attribute__((ext_vector_type(4))) float f32x4;

__device__ __forceinline__ f32x4 mfma16h(f16x8 a, f16x8 b, f32x4 c) {
  return __builtin_amdgcn_mfma_f32_16x16x32_f16(a, b, c, 0, 0, 0);
}
__device__ __forceinline__ void g2l16(const void* g, void* l) {
  __builtin_amdgcn_global_load_lds(
      (const __attribute__((address_space(1))) void*)g,
      (__attribute__((address_space(3))) void*)l,
      16, 0, 0);
}

// ---------------------------------------------------------------------------
// K0: fp32 -> fp16 for X and Wq/Wk/Wv.
// ---------------------------------------------------------------------------
__global__ __launch_bounds__(256) void k0_cvt(
    const float* __restrict__ X,
    const float* __restrict__ Wq, const float* __restrict__ Wk,
    const float* __restrict__ Wv,
    h16* __restrict__ Xf, h16* __restrict__ Wf) {
  const int y = blockIdx.y;
  const float* src;
  h16* dst;
  int n;
  if (y == 0) {
    src = X; dst = Xf; n = 16384 * 512;
  } else {
    src = (y == 1) ? Wq : ((y == 2) ? Wk : Wv);
    dst = Wf + (size_t)(y - 1) * 512 * 512;
    n = 512 * 512;
  }
  const int i = (blockIdx.x * 256 + threadIdx.x) * 8;
  if (i >= n) return;
  float4 v0 = *(const float4*)(src + i);
  float4 v1 = *(const float4*)(src + i + 4);
  f16x8 h;
  h[0] = (h16)v0.x; h[1] = (h16)v0.y; h[2] = (h16)v0.z; h[3] = (h16)v0.w;
  h[4] = (h16)v1.x; h[5] = (h16)v1.y; h[6] = (h16)v1.z; h[7] = (h16)v1.w;
  *(f16x8*)(dst + i) = h;
}

// ---------------------------------------------------------------------------
// K1: QKV projection fp16 GEMM. Q,K row-major; V transposed Vt[b][o][s].
// ---------------------------------------------------------------------------
__global__ __launch_bounds__(256) void k1_proj(
    const h16* __restrict__ Xf, const h16* __restrict__ Wf,
    const float* __restrict__ bq, const float* __restrict__ bk,
    const float* __restrict__ bv,
    h16* __restrict__ Qf, h16* __restrict__ Kf, h16* __restrict__ Vt) {
  __shared__ h16 lA[BM * BKk], lB[BM * BKk];
  const int t = threadIdx.x;
  const int lane = t & 63;
  const int wid = t >> 6;
  const int wr = wid >> 1, wc = wid & 1;
  const int tn = blockIdx.x;
  const int m0 = blockIdx.y * BM;
  const int mat = tn >> 2;
  const int o0 = (tn & 3) * BN;
  const float* bsel = (mat == 0) ? bq : ((mat == 1) ? bk : bv);
  const size_t arow0 = (size_t)m0;
  const size_t brow0 = (size_t)mat * 512 + o0;

  f32x4 acc[4][4];
  const f32x4 fz = {0.f, 0.f, 0.f, 0.f};
#pragma unroll
  for (int m = 0; m < 4; ++m)
#pragma unroll
    for (int n = 0; n < 4; ++n) acc[m][n] = fz;

  const int srow = lane >> 3;
  const int scol = ((lane & 7) ^ srow) << 3;

  for (int k0 = 0; k0 < Hn; k0 += BKk) {
    __syncthreads();
#pragma unroll
    for (int j = 0; j < 4; ++j) {
      const int ci = wid * 4 + j;
      const int row = ci * 8 + srow;
      g2l16(Xf + (arow0 + row) * Hn + k0 + scol, &lA[ci * 512]);
      g2l16(Wf + (brow0 + row) * Hn + k0 + scol, &lB[ci * 512]);
    }
    __syncthreads();
#pragma unroll
    for (int ks = 0; ks < 2; ++ks) {
      f16x8 af[4], bf[4];
#pragma unroll
      for (int m = 0; m < 4; ++m) {
        const int row = wr * 64 + m * 16 + (lane & 15);
        const int col8 = ks * 4 + (lane >> 4);
        af[m] = *(const f16x8*)&lA[row * BKk + ((col8 ^ (row & 7)) << 3)];
      }
#pragma unroll
      for (int n = 0; n < 4; ++n) {
        const int row = wc * 64 + n * 16 + (lane & 15);
        const int col8 = ks * 4 + (lane >> 4);
        bf[n] = *(const f16x8*)&lB[row * BKk + ((col8 ^ (row & 7)) << 3)];
      }
#pragma unroll
      for (int m = 0; m < 4; ++m)
#pragma unroll
        for (int n = 0; n < 4; ++n)
          acc[m][n] = mfma16h(af[m], bf[n], acc[m][n]);
    }
  }
#pragma unroll
  for (int n = 0; n < 4; ++n) {
    const int o = o0 + wc * 64 + n * 16 + (lane & 15);
    const float bias = bsel[o];
#pragma unroll
    for (int m = 0; m < 4; ++m) {
      const int ib = m0 + wr * 64 + m * 16 + ((lane >> 4) << 2);
      if (mat < 2) {
        h16* Dst = (mat == 0) ? Qf : Kf;
#pragma unroll
        for (int r = 0; r < 4; ++r)
          Dst[(size_t)(ib + r) * Hn + o] = (h16)(acc[m][n][r] + bias);
      } else {
        const int bb = ib >> 11, s = ib & 2047;
        f16x4 p;
#pragma unroll
        for (int r = 0; r < 4; ++r) p[r] = (h16)(acc[m][n][r] + bias);
        *(f16x4*)&Vt[((size_t)bb * Hn + o) * Sn + s] = p;
      }
    }
  }
}

// ---------------------------------------------------------------------------
// K2e: exp(QK^T * scale) fp16 -> second half of each attn-row slot, plus
// per-row partial sums Par[b][q][32] (slot = blockIdx.x*2 + wc).
// No max subtraction: |score| <~ 7 -> exp <~ 1100 << fp16 max.
// ---------------------------------------------------------------------------
__global__ __launch_bounds__(256) void k2_scores(
    const h16* __restrict__ Qf, const h16* __restrict__ Kf,
    const float* __restrict__ shape_ratio,
    h16* __restrict__ S16, float* __restrict__ Par) {
  __shared__ h16 lA[BM * BKk], lB[BM * BKk];
  const int t = threadIdx.x;
  const int lane = t & 63;
  const int wid = t >> 6;
  const int wr = wid >> 1, wc = wid & 1;
  const int b = blockIdx.z;
  const int n0 = blockIdx.x * BN;
  const int m0 = blockIdx.y * BM;
  const size_t qrow0 = (size_t)b * Sn + m0;
  const size_t krow0 = (size_t)b * Sn + n0;

  f32x4 acc[4][4];
  const f32x4 fz = {0.f, 0.f, 0.f, 0.f};
#pragma unroll
  for (int m = 0; m < 4; ++m)
#pragma unroll
    for (int n = 0; n < 4; ++n) acc[m][n] = fz;

  const int srow = lane >> 3;
  const int scol = ((lane & 7) ^ srow) << 3;

  for (int k0 = 0; k0 < Hn; k0 += BKk) {
    __syncthreads();
#pragma unroll
    for (int j = 0; j < 4; ++j) {
      const int ci = wid * 4 + j;
      const int row = ci * 8 + srow;
      g2l16(Qf + (qrow0 + row) * Hn + k0 + scol, &lA[ci * 512]);
      g2l16(Kf + (krow0 + row) * Hn + k0 + scol, &lB[ci * 512]);
    }
    __syncthreads();
#pragma unroll
    for (int ks = 0; ks < 2; ++ks) {
      f16x8 af[4], bf[4];
#pragma unroll
      for (int m = 0; m < 4; ++m) {
        const int row = wr * 64 + m * 16 + (lane & 15);
        const int col8 = ks * 4 + (lane >> 4);
        af[m] = *(const f16x8*)&lA[row * BKk + ((col8 ^ (row & 7)) << 3)];
      }
#pragma unroll
      for (int n = 0; n < 4; ++n) {
        const int row = wc * 64 + n * 16 + (lane & 15);
        const int col8 = ks * 4 + (lane >> 4);
        bf[n] = *(const f16x8*)&lB[row * BKk + ((col8 ^ (row & 7)) << 3)];
      }
#pragma unroll
      for (int m = 0; m < 4; ++m)
#pragma unroll
        for (int n = 0; n < 4; ++n)
          acc[m][n] = mfma16h(af[m], bf[n], acc[m][n]);
    }
  }
  const float scale = shape_ratio[0] * 0.044194173824159216f;  // 1/sqrt(512)
  float psum[4][4];
#pragma unroll
  for (int m = 0; m < 4; ++m)
#pragma unroll
    for (int r = 0; r < 4; ++r) psum[m][r] = 0.f;

#pragma unroll
  for (int n = 0; n < 4; ++n) {
    const int kk = n0 + wc * 64 + n * 16 + (lane & 15);
#pragma unroll
    for (int m = 0; m < 4; ++m) {
      const int q = m0 + wr * 64 + m * 16 + ((lane >> 4) << 2);
#pragma unroll
      for (int r = 0; r < 4; ++r) {
        const float e = __expf(acc[m][n][r] * scale);
        S16[((size_t)b * Sn + q + r) * 4096 + 2048 + kk] = (h16)e;
        psum[m][r] += e;
      }
    }
  }
#pragma unroll
  for (int m = 0; m < 4; ++m)
#pragma unroll
    for (int r = 0; r < 4; ++r) {
      float s = psum[m][r];
      s += __shfl_xor(s, 1);
      s += __shfl_xor(s, 2);
      s += __shfl_xor(s, 4);
      s += __shfl_xor(s, 8);
      psum[m][r] = s;
    }
  if ((lane & 15) == 0) {
    const int slot = (n0 >> 6) + wc;   // blockIdx.x*2 + wc
#pragma unroll
    for (int m = 0; m < 4; ++m) {
      const int q = m0 + wr * 64 + m * 16 + ((lane >> 4) << 2);
#pragma unroll
      for (int r = 0; r < 4; ++r)
        Par[((size_t)b * Sn + q + r) * 32 + slot] = psum[m][r];
    }
  }
}

// ---------------------------------------------------------------------------
// K4p: ctx[b] = (exp . V) * inv(rowsum).  128x128 tile, K=2048.
// Reads raw fp16 exp from the attn-region stash (row stride 4096, off 2048).
// Runs BEFORE k3n (which clobbers the stash).
// ---------------------------------------------------------------------------
__global__ __launch_bounds__(256) void k4_pv(
    const h16* __restrict__ S16, const float* __restrict__ Par,
    const h16* __restrict__ Vt, float* __restrict__ Ctx) {
  __shared__ h16 lA[BM * BKk], lB[BM * BKk];
  __shared__ float invSh[BM];
  const int t = threadIdx.x;
  const int lane = t & 63;
  const int wid = t >> 6;
  const int wr = wid >> 1, wc = wid & 1;
  const int b = blockIdx.z;
  const int n0 = blockIdx.x * BN;     // h tile
  const int m0 = blockIdx.y * BM;     // q tile

  // prologue: per-row inv sums (amortized over K=2048 loop)
  if (t < BM) {
    const float* p = Par + ((size_t)b * Sn + m0 + t) * 32;
    float s = 0.f;
#pragma unroll
    for (int i = 0; i < 32; ++i) s += p[i];
    invSh[t] = 1.0f / s;
  }

  f32x4 acc[4][4];
  const f32x4 fz = {0.f, 0.f, 0.f, 0.f};
#pragma unroll
  for (int m = 0; m < 4; ++m)
#pragma unroll
    for (int n = 0; n < 4; ++n) acc[m][n] = fz;

  const int srow = lane >> 3;
  const int scol = ((lane & 7) ^ srow) << 3;

  for (int k0 = 0; k0 < Sn; k0 += BKk) {
    __syncthreads();
#pragma unroll
    for (int j = 0; j < 4; ++j) {
      const int ci = wid * 4 + j;
      const int row = ci * 8 + srow;
      g2l16(S16 + ((size_t)(b * Sn + m0 + row)) * 4096 + 2048 + k0 + scol,
            &lA[ci * 512]);
      g2l16(Vt + ((size_t)b * Hn + n0 + row) * Sn + k0 + scol, &lB[ci * 512]);
    }
    __syncthreads();
#pragma unroll
    for (int ks = 0; ks < 2; ++ks) {
      f16x8 af[4], bf[4];
#pragma unroll
      for (int m = 0; m < 4; ++m) {
        const int row = wr * 64 + m * 16 + (lane & 15);
        const int col8 = ks * 4 + (lane >> 4);
        af[m] = *(const f16x8*)&lA[row * BKk + ((col8 ^ (row & 7)) << 3)];
      }
#pragma unroll
      for (int n = 0; n < 4; ++n) {
        const int row = wc * 64 + n * 16 + (lane & 15);
        const int col8 = ks * 4 + (lane >> 4);
        bf[n] = *(const f16x8*)&lB[row * BKk + ((col8 ^ (row & 7)) << 3)];
      }
#pragma unroll
      for (int m = 0; m < 4; ++m)
#pragma unroll
        for (int n = 0; n < 4; ++n)
          acc[m][n] = mfma16h(af[m], bf[n], acc[m][n]);
    }
  }
#pragma unroll
  for (int n = 0; n < 4; ++n) {
    const int h = n0 + wc * 64 + n * 16 + (lane & 15);
#pragma unroll
    for (int m = 0; m < 4; ++m) {
      const int qb = wr * 64 + m * 16 + ((lane >> 4) << 2);  // local row
#pragma unroll
      for (int r = 0; r < 4; ++r)
        Ctx[((size_t)(b * Sn + m0 + qb + r)) * Hn + h] =
            acc[m][n][r] * invSh[qb + r];
    }
  }
}

// ---------------------------------------------------------------------------
// K3n: attn fp32 row = exp fp16 * inv(rowsum).  One row per block; reads the
// exp stash into regs, syncs, overwrites the full 8KB fp32 slot.
// ---------------------------------------------------------------------------
__global__ __launch_bounds__(256) void k3_norm(
    const float* __restrict__ Par, float* __restrict__ attnF) {
  const int r = blockIdx.x;              // global row, 0..16383
  const int t = threadIdx.x;
  float* row = attnF + (size_t)r * Sn;
  const h16* erow = (const h16*)row + 2048;   // second-half stash

  f16x8 e = *(const f16x8*)(erow + t * 8);

  __shared__ float shInv;
  float s = (t < 32) ? Par[(size_t)r * 32 + t] : 0.f;
  if (t < 64) {
    s += __shfl_xor(s, 32);
    s += __shfl_xor(s, 16);
    s += __shfl_xor(s, 8);
    s += __shfl_xor(s, 4);
    s += __shfl_xor(s, 2);
    s += __shfl_xor(s, 1);
    if (t == 0) shInv = 1.0f / s;
  }
  __syncthreads();                        // e-loads done; inv ready
  const float iv = shInv;

  float4 o0 = make_float4((float)e[0] * iv, (float)e[1] * iv,
                          (float)e[2] * iv, (float)e[3] * iv);
  float4 o1 = make_float4((float)e[4] * iv, (float)e[5] * iv,
                          (float)e[6] * iv, (float)e[7] * iv);
  *(float4*)(row + t * 8) = o0;
  *(float4*)(row + t * 8 + 4) = o1;
}

// ---------------------------------------------------------------------------
extern "C" void kernel_launch(void* const* d_in, const int* in_sizes, int n_in,
                              void* d_out, int out_size, void* d_ws, size_t ws_size,
                              hipStream_t stream) {
  const float* X  = (const float*)d_in[0];
  // d_in[1] = event_flag (cancels in softmax), d_in[2] = lengths (unused)
  const float* Wq = (const float*)d_in[3];
  const float* bq = (const float*)d_in[4];
  const float* Wk = (const float*)d_in[5];
  const float* bk = (const float*)d_in[6];
  const float* Wv = (const float*)d_in[7];
  const float* bv = (const float*)d_in[8];
  // d_in[9] = event_weight (cancels in softmax)
  const float* shape_ratio = (const float*)d_in[10];

  float* ctx  = (float*)d_out;
  float* attn = ctx + (size_t)Bn * Sn * Hn;

  h16* ws = (h16*)d_ws;
  const size_t A = (size_t)Bn * Sn * Hn;   // 8,388,608
  const size_t W3 = (size_t)3 * 512 * 512; // 786,432
  h16* Xf = ws;
  h16* Wf = ws + A;
  h16* Qf = ws + A + W3;
  h16* Kf = ws + 2 * A + W3;
  float* Par = (float*)(ws + 3 * A + W3);  // 8*2048*32 floats = 2 MB
  h16* Vt = ws + 4 * A;

  k0_cvt<<<dim3(4096, 4), 256, 0, stream>>>(X, Wq, Wk, Wv, Xf, Wf);
  k1_proj<<<dim3(12, 128), 256, 0, stream>>>(Xf, Wf, bq, bk, bv, Qf, Kf, Vt);
  k2_scores<<<dim3(16, 16, 8), 256, 0, stream>>>(Qf, Kf, shape_ratio,
                                                 (h16*)attn, Par);
  k4_pv<<<dim3(4, 16, 8), 256, 0, stream>>>((const h16*)attn, Par, Vt, ctx);
  k3_norm<<<dim3(Bn * Sn), 256, 0, stream>>>(Par, attn);
}

// Round 6
// 190.493 us; speedup vs baseline: 1.1469x; 1.1365x over previous
//
#include <hip/hip_runtime.h>
#include <stdint.h>

// EventAwareAttention: B=8, S=2048, H=DK=512
// d_out = [context fp32 (8*2048*512)] ++ [attn fp32 (8*2048*2048)]
// Pipeline:
//   k0  cvt fp32->fp16 (X, W)
//   k1  QKV proj fp16 GEMM (XCD-pinned m-ranges)
//   k2e QK^T + exp + per-row partial sums (XCD = batch); exp fp16 stashed in
//       the SECOND half of each attn row's 8KB fp32 slot
//   k4p PV GEMM on raw exp (XCD = batch), ctx = acc * inv(rowsum)
//   k3n normalize: attn fp32 rows = exp * inv   [clobbers exp stash]
// ws (h16 units, A=8388608): Xf[0,A) | Wf | Qf | Kf | Par(2MB f32) | Vt[4A,5A)

#define Bn 8
#define Sn 2048
#define Hn 512
#define BM 128
#define BN 128
#define BKk 64

typedef unsigned short u16;
typedef _Float16 h16;
typedef __attribute__((ext_vector_type(8))) _Float16 f16x8;
typedef __attribute__((ext_vector_type(4))) _Float16 f16x4;
typedef __attribute__((ext_vector_type(4))) float f32x4;

__device__ __forceinline__ f32x4 mfma16h(f16x8 a, f16x8 b, f32x4 c) {
  return __builtin_amdgcn_mfma_f32_16x16x32_f16(a, b, c, 0, 0, 0);
}
__device__ __forceinline__ void g2l16(const void* g, void* l) {
  __builtin_amdgcn_global_load_lds(
      (const __attribute__((address_space(1))) void*)g,
      (__attribute__((address_space(3))) void*)l,
      16, 0, 0);
}

// ---------------------------------------------------------------------------
// K0: fp32 -> fp16 for X and Wq/Wk/Wv.
// ---------------------------------------------------------------------------
__global__ __launch_bounds__(256) void k0_cvt(
    const float* __restrict__ X,
    const float* __restrict__ Wq, const float* __restrict__ Wk,
    const float* __restrict__ Wv,
    h16* __restrict__ Xf, h16* __restrict__ Wf) {
  const int y = blockIdx.y;
  const float* src;
  h16* dst;
  int n;
  if (y == 0) {
    src = X; dst = Xf; n = 16384 * 512;
  } else {
    src = (y == 1) ? Wq : ((y == 2) ? Wk : Wv);
    dst = Wf + (size_t)(y - 1) * 512 * 512;
    n = 512 * 512;
  }
  const int i = (blockIdx.x * 256 + threadIdx.x) * 8;
  if (i >= n) return;
  float4 v0 = *(const float4*)(src + i);
  float4 v1 = *(const float4*)(src + i + 4);
  f16x8 h;
  h[0] = (h16)v0.x; h[1] = (h16)v0.y; h[2] = (h16)v0.z; h[3] = (h16)v0.w;
  h[4] = (h16)v1.x; h[5] = (h16)v1.y; h[6] = (h16)v1.z; h[7] = (h16)v1.w;
  *(f16x8*)(dst + i) = h;
}

// ---------------------------------------------------------------------------
// K1: QKV projection fp16 GEMM. Q,K row-major; V transposed Vt[b][o][s].
// Flat grid 1536; xcd = l&7 owns m-tiles [xcd*16, xcd*16+16) x 12 tn-blocks
// -> X-slice (2MB) + W (1.5MB) L2-resident per XCD.
// ---------------------------------------------------------------------------
__global__ __launch_bounds__(256) void k1_proj(
    const h16* __restrict__ Xf, const h16* __restrict__ Wf,
    const float* __restrict__ bq, const float* __restrict__ bk,
    const float* __restrict__ bv,
    h16* __restrict__ Qf, h16* __restrict__ Kf, h16* __restrict__ Vt) {
  __shared__ h16 lA[BM * BKk], lB[BM * BKk];
  const int t = threadIdx.x;
  const int lane = t & 63;
  const int wid = t >> 6;
  const int wr = wid >> 1, wc = wid & 1;
  const int l = blockIdx.x;
  const int xcd = l & 7;
  const int slot = l >> 3;            // 0..191
  const int m_idx = xcd * 16 + slot / 12;
  const int tn = slot % 12;           // 0..11: [Q0..3 K0..3 V0..3]
  const int m0 = m_idx * BM;
  const int mat = tn >> 2;
  const int o0 = (tn & 3) * BN;
  const float* bsel = (mat == 0) ? bq : ((mat == 1) ? bk : bv);
  const size_t arow0 = (size_t)m0;
  const size_t brow0 = (size_t)mat * 512 + o0;

  f32x4 acc[4][4];
  const f32x4 fz = {0.f, 0.f, 0.f, 0.f};
#pragma unroll
  for (int m = 0; m < 4; ++m)
#pragma unroll
    for (int n = 0; n < 4; ++n) acc[m][n] = fz;

  const int srow = lane >> 3;
  const int scol = ((lane & 7) ^ srow) << 3;

  for (int k0 = 0; k0 < Hn; k0 += BKk) {
    __syncthreads();
#pragma unroll
    for (int j = 0; j < 4; ++j) {
      const int ci = wid * 4 + j;
      const int row = ci * 8 + srow;
      g2l16(Xf + (arow0 + row) * Hn + k0 + scol, &lA[ci * 512]);
      g2l16(Wf + (brow0 + row) * Hn + k0 + scol, &lB[ci * 512]);
    }
    __syncthreads();
#pragma unroll
    for (int ks = 0; ks < 2; ++ks) {
      f16x8 af[4], bf[4];
#pragma unroll
      for (int m = 0; m < 4; ++m) {
        const int row = wr * 64 + m * 16 + (lane & 15);
        const int col8 = ks * 4 + (lane >> 4);
        af[m] = *(const f16x8*)&lA[row * BKk + ((col8 ^ (row & 7)) << 3)];
      }
#pragma unroll
      for (int n = 0; n < 4; ++n) {
        const int row = wc * 64 + n * 16 + (lane & 15);
        const int col8 = ks * 4 + (lane >> 4);
        bf[n] = *(const f16x8*)&lB[row * BKk + ((col8 ^ (row & 7)) << 3)];
      }
#pragma unroll
      for (int m = 0; m < 4; ++m)
#pragma unroll
        for (int n = 0; n < 4; ++n)
          acc[m][n] = mfma16h(af[m], bf[n], acc[m][n]);
    }
  }
#pragma unroll
  for (int n = 0; n < 4; ++n) {
    const int o = o0 + wc * 64 + n * 16 + (lane & 15);
    const float bias = bsel[o];
#pragma unroll
    for (int m = 0; m < 4; ++m) {
      const int ib = m0 + wr * 64 + m * 16 + ((lane >> 4) << 2);
      if (mat < 2) {
        h16* Dst = (mat == 0) ? Qf : Kf;
#pragma unroll
        for (int r = 0; r < 4; ++r)
          Dst[(size_t)(ib + r) * Hn + o] = (h16)(acc[m][n][r] + bias);
      } else {
        const int bb = ib >> 11, s = ib & 2047;
        f16x4 p;
#pragma unroll
        for (int r = 0; r < 4; ++r) p[r] = (h16)(acc[m][n][r] + bias);
        *(f16x4*)&Vt[((size_t)bb * Hn + o) * Sn + s] = p;
      }
    }
  }
}

// ---------------------------------------------------------------------------
// K2e: exp(QK^T * scale) fp16 -> second half of each attn-row slot, plus
// per-row partial sums Par[b][q][32] (slot = n*2 + wc).
// Flat grid 2048; xcd = l&7 = batch -> K-panel (2MB) L2-resident; 16
// consecutive slots share the Q m-tile.
// No max subtraction: |score| <~ 7 -> exp <~ 1100 << fp16 max.
// ---------------------------------------------------------------------------
__global__ __launch_bounds__(256) void k2_scores(
    const h16* __restrict__ Qf, const h16* __restrict__ Kf,
    const float* __restrict__ shape_ratio,
    h16* __restrict__ S16, float* __restrict__ Par) {
  __shared__ h16 lA[BM * BKk], lB[BM * BKk];
  const int t = threadIdx.x;
  const int lane = t & 63;
  const int wid = t >> 6;
  const int wr = wid >> 1, wc = wid & 1;
  const int l = blockIdx.x;
  const int b = l & 7;                 // batch -> XCD
  const int slot = l >> 3;             // 0..255
  const int mi = slot >> 4;            // m-tile 0..15
  const int ni = slot & 15;            // n-tile 0..15
  const int n0 = ni * BN;
  const int m0 = mi * BM;
  const size_t qrow0 = (size_t)b * Sn + m0;
  const size_t krow0 = (size_t)b * Sn + n0;

  f32x4 acc[4][4];
  const f32x4 fz = {0.f, 0.f, 0.f, 0.f};
#pragma unroll
  for (int m = 0; m < 4; ++m)
#pragma unroll
    for (int n = 0; n < 4; ++n) acc[m][n] = fz;

  const int srow = lane >> 3;
  const int scol = ((lane & 7) ^ srow) << 3;

  for (int k0 = 0; k0 < Hn; k0 += BKk) {
    __syncthreads();
#pragma unroll
    for (int j = 0; j < 4; ++j) {
      const int ci = wid * 4 + j;
      const int row = ci * 8 + srow;
      g2l16(Qf + (qrow0 + row) * Hn + k0 + scol, &lA[ci * 512]);
      g2l16(Kf + (krow0 + row) * Hn + k0 + scol, &lB[ci * 512]);
    }
    __syncthreads();
#pragma unroll
    for (int ks = 0; ks < 2; ++ks) {
      f16x8 af[4], bf[4];
#pragma unroll
      for (int m = 0; m < 4; ++m) {
        const int row = wr * 64 + m * 16 + (lane & 15);
        const int col8 = ks * 4 + (lane >> 4);
        af[m] = *(const f16x8*)&lA[row * BKk + ((col8 ^ (row & 7)) << 3)];
      }
#pragma unroll
      for (int n = 0; n < 4; ++n) {
        const int row = wc * 64 + n * 16 + (lane & 15);
        const int col8 = ks * 4 + (lane >> 4);
        bf[n] = *(const f16x8*)&lB[row * BKk + ((col8 ^ (row & 7)) << 3)];
      }
#pragma unroll
      for (int m = 0; m < 4; ++m)
#pragma unroll
        for (int n = 0; n < 4; ++n)
          acc[m][n] = mfma16h(af[m], bf[n], acc[m][n]);
    }
  }
  const float scale = shape_ratio[0] * 0.044194173824159216f;  // 1/sqrt(512)
  float psum[4][4];
#pragma unroll
  for (int m = 0; m < 4; ++m)
#pragma unroll
    for (int r = 0; r < 4; ++r) psum[m][r] = 0.f;

#pragma unroll
  for (int n = 0; n < 4; ++n) {
    const int kk = n0 + wc * 64 + n * 16 + (lane & 15);
#pragma unroll
    for (int m = 0; m < 4; ++m) {
      const int q = m0 + wr * 64 + m * 16 + ((lane >> 4) << 2);
#pragma unroll
      for (int r = 0; r < 4; ++r) {
        const float e = __expf(acc[m][n][r] * scale);
        S16[((size_t)b * Sn + q + r) * 4096 + 2048 + kk] = (h16)e;
        psum[m][r] += e;
      }
    }
  }
#pragma unroll
  for (int m = 0; m < 4; ++m)
#pragma unroll
    for (int r = 0; r < 4; ++r) {
      float s = psum[m][r];
      s += __shfl_xor(s, 1);
      s += __shfl_xor(s, 2);
      s += __shfl_xor(s, 4);
      s += __shfl_xor(s, 8);
      psum[m][r] = s;
    }
  if ((lane & 15) == 0) {
    const int pslot = ni * 2 + wc;
#pragma unroll
    for (int m = 0; m < 4; ++m) {
      const int q = m0 + wr * 64 + m * 16 + ((lane >> 4) << 2);
#pragma unroll
      for (int r = 0; r < 4; ++r)
        Par[((size_t)b * Sn + q + r) * 32 + pslot] = psum[m][r];
    }
  }
}

// ---------------------------------------------------------------------------
// K4p: ctx[b] = (exp . V) * inv(rowsum).  128x128 tile, K=2048.
// Flat grid 512; xcd = l&7 = batch; 4 consecutive slots share the exp
// m-panel (512KB, L2-hit) and V (2MB, L2-resident).
// Runs BEFORE k3n (which clobbers the exp stash).
// ---------------------------------------------------------------------------
__global__ __launch_bounds__(256) void k4_pv(
    const h16* __restrict__ S16, const float* __restrict__ Par,
    const h16* __restrict__ Vt, float* __restrict__ Ctx) {
  __shared__ h16 lA[BM * BKk], lB[BM * BKk];
  __shared__ float invSh[BM];
  const int t = threadIdx.x;
  const int lane = t & 63;
  const int wid = t >> 6;
  const int wr = wid >> 1, wc = wid & 1;
  const int l = blockIdx.x;
  const int b = l & 7;                 // batch -> XCD
  const int slot = l >> 3;             // 0..63
  const int mi = slot >> 2;            // 0..15
  const int ni = slot & 3;             // 0..3
  const int n0 = ni * BN;              // h tile
  const int m0 = mi * BM;              // q tile

  if (t < BM) {
    const float* p = Par + ((size_t)b * Sn + m0 + t) * 32;
    float s = 0.f;
#pragma unroll
    for (int i = 0; i < 32; ++i) s += p[i];
    invSh[t] = 1.0f / s;
  }

  f32x4 acc[4][4];
  const f32x4 fz = {0.f, 0.f, 0.f, 0.f};
#pragma unroll
  for (int m = 0; m < 4; ++m)
#pragma unroll
    for (int n = 0; n < 4; ++n) acc[m][n] = fz;

  const int srow = lane >> 3;
  const int scol = ((lane & 7) ^ srow) << 3;

  for (int k0 = 0; k0 < Sn; k0 += BKk) {
    __syncthreads();
#pragma unroll
    for (int j = 0; j < 4; ++j) {
      const int ci = wid * 4 + j;
      const int row = ci * 8 + srow;
      g2l16(S16 + ((size_t)(b * Sn + m0 + row)) * 4096 + 2048 + k0 + scol,
            &lA[ci * 512]);
      g2l16(Vt + ((size_t)b * Hn + n0 + row) * Sn + k0 + scol, &lB[ci * 512]);
    }
    __syncthreads();
#pragma unroll
    for (int ks = 0; ks < 2; ++ks) {
      f16x8 af[4], bf[4];
#pragma unroll
      for (int m = 0; m < 4; ++m) {
        const int row = wr * 64 + m * 16 + (lane & 15);
        const int col8 = ks * 4 + (lane >> 4);
        af[m] = *(const f16x8*)&lA[row * BKk + ((col8 ^ (row & 7)) << 3)];
      }
#pragma unroll
      for (int n = 0; n < 4; ++n) {
        const int row = wc * 64 + n * 16 + (lane & 15);
        const int col8 = ks * 4 + (lane >> 4);
        bf[n] = *(const f16x8*)&lB[row * BKk + ((col8 ^ (row & 7)) << 3)];
      }
#pragma unroll
      for (int m = 0; m < 4; ++m)
#pragma unroll
        for (int n = 0; n < 4; ++n)
          acc[m][n] = mfma16h(af[m], bf[n], acc[m][n]);
    }
  }
#pragma unroll
  for (int n = 0; n < 4; ++n) {
    const int h = n0 + wc * 64 + n * 16 + (lane & 15);
#pragma unroll
    for (int m = 0; m < 4; ++m) {
      const int qb = wr * 64 + m * 16 + ((lane >> 4) << 2);  // local row
#pragma unroll
      for (int r = 0; r < 4; ++r)
        Ctx[((size_t)(b * Sn + m0 + qb + r)) * Hn + h] =
            acc[m][n][r] * invSh[qb + r];
    }
  }
}

// ---------------------------------------------------------------------------
// K3n: attn fp32 row = exp fp16 * inv(rowsum).  One row per block; reads the
// exp stash into regs, syncs, overwrites the full 8KB fp32 slot.
// ---------------------------------------------------------------------------
__global__ __launch_bounds__(256) void k3_norm(
    const float* __restrict__ Par, float* __restrict__ attnF) {
  const int r = blockIdx.x;              // global row, 0..16383
  const int t = threadIdx.x;
  float* row = attnF + (size_t)r * Sn;
  const h16* erow = (const h16*)row + 2048;   // second-half stash

  f16x8 e = *(const f16x8*)(erow + t * 8);

  __shared__ float shInv;
  float s = (t < 32) ? Par[(size_t)r * 32 + t] : 0.f;
  if (t < 64) {
    s += __shfl_xor(s, 32);
    s += __shfl_xor(s, 16);
    s += __shfl_xor(s, 8);
    s += __shfl_xor(s, 4);
    s += __shfl_xor(s, 2);
    s += __shfl_xor(s, 1);
    if (t == 0) shInv = 1.0f / s;
  }
  __syncthreads();                        // e-loads done; inv ready
  const float iv = shInv;

  float4 o0 = make_float4((float)e[0] * iv, (float)e[1] * iv,
                          (float)e[2] * iv, (float)e[3] * iv);
  float4 o1 = make_float4((float)e[4] * iv, (float)e[5] * iv,
                          (float)e[6] * iv, (float)e[7] * iv);
  *(float4*)(row + t * 8) = o0;
  *(float4*)(row + t * 8 + 4) = o1;
}

// ---------------------------------------------------------------------------
extern "C" void kernel_launch(void* const* d_in, const int* in_sizes, int n_in,
                              void* d_out, int out_size, void* d_ws, size_t ws_size,
                              hipStream_t stream) {
  const float* X  = (const float*)d_in[0];
  // d_in[1] = event_flag (cancels in softmax), d_in[2] = lengths (unused)
  const float* Wq = (const float*)d_in[3];
  const float* bq = (const float*)d_in[4];
  const float* Wk = (const float*)d_in[5];
  const float* bk = (const float*)d_in[6];
  const float* Wv = (const float*)d_in[7];
  const float* bv = (const float*)d_in[8];
  // d_in[9] = event_weight (cancels in softmax)
  const float* shape_ratio = (const float*)d_in[10];

  float* ctx  = (float*)d_out;
  float* attn = ctx + (size_t)Bn * Sn * Hn;

  h16* ws = (h16*)d_ws;
  const size_t A = (size_t)Bn * Sn * Hn;   // 8,388,608
  const size_t W3 = (size_t)3 * 512 * 512; // 786,432
  h16* Xf = ws;
  h16* Wf = ws + A;
  h16* Qf = ws + A + W3;
  h16* Kf = ws + 2 * A + W3;
  float* Par = (float*)(ws + 3 * A + W3);  // 8*2048*32 floats = 2 MB
  h16* Vt = ws + 4 * A;

  k0_cvt<<<dim3(4096, 4), 256, 0, stream>>>(X, Wq, Wk, Wv, Xf, Wf);
  k1_proj<<<dim3(1536), 256, 0, stream>>>(Xf, Wf, bq, bk, bv, Qf, Kf, Vt);
  k2_scores<<<dim3(2048), 256, 0, stream>>>(Qf, Kf, shape_ratio,
                                            (h16*)attn, Par);
  k4_pv<<<dim3(512), 256, 0, stream>>>((const h16*)attn, Par, Vt, ctx);
  k3_norm<<<dim3(Bn * Sn), 256, 0, stream>>>(Par, attn);
}